// Round 8
// baseline (297.198 us; speedup 1.0000x reference)
//
#include <hip/hip_runtime.h>

typedef unsigned int uint;
typedef __attribute__((ext_vector_type(8))) short bf16x8;
typedef __attribute__((ext_vector_type(4))) float f32x4;

__device__ __forceinline__ float b2f(ushort h) { return __uint_as_float(((uint)h) << 16); }
__device__ __forceinline__ ushort f2b(float f) {
    uint u = __float_as_uint(f);
    return (ushort)((u + 0x7fffu + ((u >> 16) & 1u)) >> 16);
}

#define NBLK_S 256   // sort blocks (pass A / pass C)

// ================= fused prep: f2b(x) | wtrans | pass A (LDS bucket hist) =================
__global__ __launch_bounds__(1024) void prep_k(
    const float* __restrict__ x, ushort* __restrict__ xb, long n8,
    const float* __restrict__ W1, const float* __restrict__ W2,
    const float* __restrict__ W3, const float* __restrict__ b3,
    ushort* __restrict__ Wt1, ushort* __restrict__ Wt2,
    ushort* __restrict__ Wt3, float* __restrict__ b3p, int NC,
    const int* __restrict__ d1, const int* __restrict__ d2, const int* __restrict__ d3,
    int E1, int E2, int E3, int n1, int n2,
    int* __restrict__ bh, int NBKT, int chunk, int Gf2b) {
    __shared__ int hist[2048];
    int b = blockIdx.x;
    if (b < Gf2b) {
        long i = (long)b * 1024 + threadIdx.x;
        long st = (long)Gf2b * 1024;
        for (; i < n8; i += st) {
            float4 a = reinterpret_cast<const float4*>(x)[i * 2];
            float4 c = reinterpret_cast<const float4*>(x)[i * 2 + 1];
            ushort4 o0, o1;
            o0.x = f2b(a.x); o0.y = f2b(a.y); o0.z = f2b(a.z); o0.w = f2b(a.w);
            o1.x = f2b(c.x); o1.y = f2b(c.y); o1.z = f2b(c.z); o1.w = f2b(c.w);
            reinterpret_cast<ushort4*>(xb)[i * 2] = o0;
            reinterpret_cast<ushort4*>(xb)[i * 2 + 1] = o1;
        }
        return;
    }
    b -= Gf2b;
    if (b < 256) {
        int k = b;
        int t = threadIdx.x;
        if (t < 256) {
            Wt1[(long)t * 256 + k] = f2b(W1[(long)k * 256 + t]);
        } else if (t < 512) {
            int n = t - 256;
            Wt2[(long)n * 256 + k] = f2b(W2[(long)k * 256 + n]);
        } else if (t < 640) {
            int n = t - 512;
            float v = (n < NC) ? W3[(long)k * NC + n] : 0.f;
            Wt3[(long)n * 256 + k] = f2b(v);
            if (k == 0) b3p[n] = (n < NC) ? b3[n] : 0.f;
        }
        return;
    }
    b -= 256;
    const int Et = E1 + E2 + E3;
    const int c0 = b * chunk;
    const int c1 = (c0 + chunk < Et) ? c0 + chunk : Et;
    for (int i = threadIdx.x; i < NBKT; i += 1024) hist[i] = 0;
    __syncthreads();
    for (int i = c0 + (int)threadIdx.x; i < c1; i += 1024) {
        int g;
        if (i < E1) g = d1[i];
        else if (i < E1 + E2) g = n1 + d2[i - E1];
        else g = n1 + n2 + d3[i - E1 - E2];
        atomicAdd(&hist[g >> 6], 1);
    }
    __syncthreads();
    for (int k = threadIdx.x; k < NBKT; k += 1024) bh[k * NBLK_S + b] = hist[k];
}

// ---- scan phase 1 ----
__global__ __launch_bounds__(1024) void scan1(const int* __restrict__ cnt, int* __restrict__ off,
                                              int* __restrict__ bsum, int n) {
    __shared__ int wsum[16];
    const int lane = threadIdx.x & 63;
    const int wid = threadIdx.x >> 6;
    int i = blockIdx.x * 1024 + threadIdx.x;
    int v = (i < n) ? cnt[i] : 0;
    int s = v;
    #pragma unroll
    for (int o = 1; o < 64; o <<= 1) {
        int t = __shfl_up(s, o, 64);
        if (lane >= o) s += t;
    }
    if (lane == 63) wsum[wid] = s;
    __syncthreads();
    if (wid == 0 && lane < 16) {
        int t = wsum[lane];
        #pragma unroll
        for (int o = 1; o < 16; o <<= 1) {
            int u = __shfl_up(t, o, 64);
            if (lane >= o) t += u;
        }
        wsum[lane] = t;
    }
    __syncthreads();
    int woff = (wid > 0) ? wsum[wid - 1] : 0;
    if (i < n) off[i] = woff + s - v;
    if (threadIdx.x == 0) bsum[blockIdx.x] = wsum[15];
}

// ---- scan phase 2 ----
__global__ __launch_bounds__(1024) void scan2b(const int* __restrict__ bsum, int* __restrict__ bbase,
                                               int n, int* __restrict__ offNT, float* __restrict__ acc) {
    __shared__ int wsum[16];
    int tid = threadIdx.x;
    int lane = tid & 63;
    int wid = tid >> 6;
    int v = (tid < n) ? bsum[tid] : 0;
    int s = v;
    #pragma unroll
    for (int o = 1; o < 64; o <<= 1) {
        int t = __shfl_up(s, o, 64);
        if (lane >= o) s += t;
    }
    if (lane == 63) wsum[wid] = s;
    __syncthreads();
    if (wid == 0 && lane < 16) {
        int t = wsum[lane];
        #pragma unroll
        for (int o = 1; o < 16; o <<= 1) {
            int u = __shfl_up(t, o, 64);
            if (lane >= o) t += u;
        }
        wsum[lane] = t;
    }
    __syncthreads();
    int base = (wid > 0) ? wsum[wid - 1] : 0;
    int excl = base + s - v;
    if (tid < n) bbase[tid] = excl;
    if (tid == n - 1) *offNT = excl + v;
    if (tid == 0) *acc = 0.f;
}

// ---- scan phase 3 ----
__global__ __launch_bounds__(256) void scan3(int* __restrict__ a, const int* __restrict__ bbase, int n) {
    int i = blockIdx.x * 256 + threadIdx.x;
    int st = gridDim.x * 256;
    for (; i < n; i += st) a[i] += bbase[i >> 10];
}

// ================= pass C: place edges bucket-sorted =================
__global__ __launch_bounds__(1024) void sortC(
    const int* __restrict__ s1, const int* __restrict__ d1,
    const int* __restrict__ s2, const int* __restrict__ d2,
    const int* __restrict__ s3, const int* __restrict__ d3,
    const float* __restrict__ w1, const float* __restrict__ w2, const float* __restrict__ w3,
    const int* __restrict__ bhs, int* __restrict__ bs_g, int2* __restrict__ bs_sw,
    int E1, int E2, int E3, int n1, int n2, int NBKT, int chunk) {
    __shared__ int cur[2048];
    const int b = blockIdx.x;
    const int Et = E1 + E2 + E3;
    const int c0 = b * chunk;
    const int c1 = (c0 + chunk < Et) ? c0 + chunk : Et;
    for (int k = threadIdx.x; k < NBKT; k += 1024) cur[k] = bhs[k * NBLK_S + b];
    __syncthreads();
    for (int i = c0 + (int)threadIdx.x; i < c1; i += 1024) {
        int g, s, w;
        if (i < E1) { g = d1[i]; s = s1[i]; w = __float_as_int(w1[i]); }
        else if (i < E1 + E2) { int j = i - E1; g = n1 + d2[j]; s = s2[j]; w = __float_as_int(w2[j]); }
        else { int j = i - E1 - E2; g = n1 + n2 + d3[j]; s = s3[j]; w = __float_as_int(w3[j]); }
        int p = atomicAdd(&cur[g >> 6], 1);
        bs_g[p] = g;
        bs_sw[p] = make_int2(s, w);
    }
}

// ================= pass D: in-bucket counting sort -> final CSR + off =================
__global__ __launch_bounds__(256) void sortD(const int* __restrict__ bhs,
                                             const int* __restrict__ bs_g,
                                             const int2* __restrict__ bs_sw,
                                             int* __restrict__ off, int2* __restrict__ csr,
                                             int NBKT, int NT, int Et) {
    __shared__ int hist[64];
    __shared__ int cur[64];
    const int b = blockIdx.x;
    const int g0 = b << 6;
    const int B0 = bhs[b * NBLK_S];
    const int B1 = (b == NBKT - 1) ? Et : bhs[(b + 1) * NBLK_S];
    const int tid = threadIdx.x;
    if (tid < 64) hist[tid] = 0;
    __syncthreads();
    for (int p = B0 + tid; p < B1; p += 256) atomicAdd(&hist[bs_g[p] - g0], 1);
    __syncthreads();
    if (tid < 64) {
        int v = hist[tid];
        int s = v;
        #pragma unroll
        for (int o = 1; o < 64; o <<= 1) {
            int t = __shfl_up(s, o, 64);
            if (tid >= o) s += t;
        }
        int excl = B0 + s - v;
        cur[tid] = excl;
        int g = g0 + tid;
        if (g < NT) off[g] = excl;
    }
    __syncthreads();
    for (int p = B0 + tid; p < B1; p += 256) {
        int r = bs_g[p] - g0;
        int q = atomicAdd(&cur[r], 1);
        csr[q] = bs_sw[p];
    }
}

// ================= gather, bf16, F == 256: scalar edge loads + half-wave pairing =================
// Wave handles one dst. Lanes 0-31 process even edge of each pair, lanes 32-63 the odd edge.
// Each lane loads ushort8 (16B) covering feats (lane&31)*8..+7. Halves combined via shfl_xor(32).
__global__ __launch_bounds__(256) void gather_b4(const ushort* __restrict__ hb,
                                                 const int* __restrict__ off,
                                                 const int2* __restrict__ csr,
                                                 ushort* __restrict__ out,
                                                 float* __restrict__ rw, int n_dst) {
    const int d = __builtin_amdgcn_readfirstlane(blockIdx.x * 4 + (threadIdx.x >> 6));
    if (d >= n_dst) return;
    const int lane = threadIdx.x & 63;
    const int half = lane >> 5;
    const int fl = lane & 31;
    const int i0 = off[d], i1 = off[d + 1];
    float acc[8] = {0.f, 0.f, 0.f, 0.f, 0.f, 0.f, 0.f, 0.f};
    float sw = 0.f;
    const ushort* hrow = hb + fl * 8;

#define PAIR_BODY(r0_, w0_, r1_, w1_)                                        \
    {                                                                         \
        int row_ = half ? (r1_) : (r0_);                                      \
        float w_ = half ? (w1_) : (w0_);                                      \
        int4 v_ = *reinterpret_cast<const int4*>(&hrow[(long)row_ * 256]);    \
        uint u_;                                                              \
        u_ = (uint)v_.x;                                                      \
        acc[0] += w_ * __uint_as_float(u_ << 16);                             \
        acc[1] += w_ * __uint_as_float(u_ & 0xffff0000u);                     \
        u_ = (uint)v_.y;                                                      \
        acc[2] += w_ * __uint_as_float(u_ << 16);                             \
        acc[3] += w_ * __uint_as_float(u_ & 0xffff0000u);                     \
        u_ = (uint)v_.z;                                                      \
        acc[4] += w_ * __uint_as_float(u_ << 16);                             \
        acc[5] += w_ * __uint_as_float(u_ & 0xffff0000u);                     \
        u_ = (uint)v_.w;                                                      \
        acc[6] += w_ * __uint_as_float(u_ << 16);                             \
        acc[7] += w_ * __uint_as_float(u_ & 0xffff0000u);                     \
        sw += (w0_) + (w1_);                                                  \
    }

    int i = i0;
    for (; i + 8 <= i1; i += 8) {          // 4 pairs = 8 edges per iteration
        int2 e[8];
        #pragma unroll
        for (int u = 0; u < 8; ++u) e[u] = csr[i + u];   // scalar (wave-uniform) loads
        #pragma unroll
        for (int p = 0; p < 4; ++p)
            PAIR_BODY(e[2 * p].x, __int_as_float(e[2 * p].y),
                      e[2 * p + 1].x, __int_as_float(e[2 * p + 1].y));
    }
    for (; i + 2 <= i1; i += 2) {
        int2 e0 = csr[i], e1 = csr[i + 1];
        PAIR_BODY(e0.x, __int_as_float(e0.y), e1.x, __int_as_float(e1.y));
    }
    if (i < i1) {                           // odd tail: hi half re-reads same row, weight 0
        int2 e0 = csr[i];
        PAIR_BODY(e0.x, __int_as_float(e0.y), e0.x, 0.f);
    }
#undef PAIR_BODY

    #pragma unroll
    for (int k = 0; k < 8; ++k) acc[k] += __shfl_xor(acc[k], 32, 64);
    if (lane == 0) rw[d] = sw;
    if (half == 0) {
        int4 o;
        o.x = (int)((uint)f2b(acc[0]) | ((uint)f2b(acc[1]) << 16));
        o.y = (int)((uint)f2b(acc[2]) | ((uint)f2b(acc[3]) << 16));
        o.z = (int)((uint)f2b(acc[4]) | ((uint)f2b(acc[5]) << 16));
        o.w = (int)((uint)f2b(acc[6]) | ((uint)f2b(acc[7]) << 16));
        *reinterpret_cast<int4*>(&out[(long)d * 256 + fl * 8]) = o;
    }
}

// ================= gather, small F (<=64), f32: scalar edge loads, ILP 8 =================
__global__ __launch_bounds__(256) void gather_small(const float* __restrict__ h,
                                                    const int* __restrict__ off,
                                                    const int2* __restrict__ csr,
                                                    float* __restrict__ y, int n_dst, int F) {
    const int d = __builtin_amdgcn_readfirstlane(blockIdx.x * 4 + (threadIdx.x >> 6));
    if (d >= n_dst) return;
    const int lane = threadIdx.x & 63;
    const int i0 = off[d], i1 = off[d + 1];
    const bool act = lane < F;
    float acc = 0.f;
    int i = i0;
    for (; i + 8 <= i1; i += 8) {
        int2 e[8];
        #pragma unroll
        for (int u = 0; u < 8; ++u) e[u] = csr[i + u];
        float v[8];
        #pragma unroll
        for (int u = 0; u < 8; ++u) v[u] = act ? h[(long)e[u].x * F + lane] : 0.f;
        #pragma unroll
        for (int u = 0; u < 8; ++u) acc += __int_as_float(e[u].y) * v[u];
    }
    for (; i < i1; ++i) {
        int2 e = csr[i];
        if (act) acc += __int_as_float(e.y) * h[(long)e.x * F + lane];
    }
    if (act) y[(long)d * F + lane] = acc;
}

// ================= bf16 MFMA GEMM: C = act(A @ Bt^T + rowsc⊗bias) =================
template <bool RELU, bool OUTF32, bool ROWSC, bool GUARDN>
__global__ __launch_bounds__(256) void gemm_mfma(const ushort* __restrict__ A,
                                                 const ushort* __restrict__ Bt,
                                                 const float* __restrict__ bias,
                                                 const float* __restrict__ rowsc,
                                                 ushort* __restrict__ Cb,
                                                 float* __restrict__ Cf,
                                                 int M, int Nout, int K) {
    __shared__ ushort As[4096];
    __shared__ ushort Bs[4096];
    const int tid = threadIdx.x;
    const int w = tid >> 6;
    const int lane = tid & 63;
    const int l15 = lane & 15;
    const int l4 = lane >> 4;
    const int bm = blockIdx.x * 128;
    const int bn = blockIdx.y * 128;
    const int wm = w >> 1, wn = w & 1;

    int ra0 = bm + w * 16 + l15;       if (ra0 >= M) ra0 = M - 1;
    int ra1 = bm + (w + 4) * 16 + l15; if (ra1 >= M) ra1 = M - 1;
    const ushort* pa0 = A + (long)ra0 * K + l4 * 8;
    const ushort* pa1 = A + (long)ra1 * K + l4 * 8;
    const ushort* pb0 = Bt + (long)(bn + w * 16 + l15) * K + l4 * 8;
    const ushort* pb1 = Bt + (long)(bn + (w + 4) * 16 + l15) * K + l4 * 8;

    f32x4 acc[4][4];
    f32x4 zz = {0.f, 0.f, 0.f, 0.f};
    #pragma unroll
    for (int m = 0; m < 4; ++m)
        #pragma unroll
        for (int n = 0; n < 4; ++n) acc[m][n] = zz;

    for (int k0 = 0; k0 < K; k0 += 32) {
        __builtin_amdgcn_global_load_lds((const __attribute__((address_space(1))) void*)pa0,
                                         (__attribute__((address_space(3))) void*)&As[w * 512], 16, 0, 0);
        __builtin_amdgcn_global_load_lds((const __attribute__((address_space(1))) void*)pa1,
                                         (__attribute__((address_space(3))) void*)&As[(w + 4) * 512], 16, 0, 0);
        __builtin_amdgcn_global_load_lds((const __attribute__((address_space(1))) void*)pb0,
                                         (__attribute__((address_space(3))) void*)&Bs[w * 512], 16, 0, 0);
        __builtin_amdgcn_global_load_lds((const __attribute__((address_space(1))) void*)pb1,
                                         (__attribute__((address_space(3))) void*)&Bs[(w + 4) * 512], 16, 0, 0);
        pa0 += 32; pa1 += 32; pb0 += 32; pb1 += 32;
        __syncthreads();
        bf16x8 af[4], bfr[4];
        #pragma unroll
        for (int m = 0; m < 4; ++m)
            af[m] = *reinterpret_cast<const bf16x8*>(&As[(wm * 4 + m) * 512 + lane * 8]);
        #pragma unroll
        for (int n = 0; n < 4; ++n)
            bfr[n] = *reinterpret_cast<const bf16x8*>(&Bs[(wn * 4 + n) * 512 + lane * 8]);
        #pragma unroll
        for (int m = 0; m < 4; ++m)
            #pragma unroll
            for (int n = 0; n < 4; ++n)
                acc[m][n] = __builtin_amdgcn_mfma_f32_16x16x32_bf16(af[m], bfr[n], acc[m][n], 0, 0, 0);
        __syncthreads();
    }

    const int rbase = bm + wm * 64;
    const int cbase = bn + wn * 64;
    #pragma unroll
    for (int m = 0; m < 4; ++m) {
        #pragma unroll
        for (int q = 0; q < 4; ++q) {
            int r = rbase + m * 16 + l4 * 4 + q;
            if (r >= M) continue;
            float rs = ROWSC ? rowsc[r] : 1.f;
            #pragma unroll
            for (int n = 0; n < 4; ++n) {
                int c = cbase + n * 16 + l15;
                float v = acc[m][n][q] + rs * bias[c];
                if (RELU) v = fmaxf(v, 0.f);
                if (!GUARDN || c < Nout) {
                    if (OUTF32) Cf[(long)r * Nout + c] = v;
                    else Cb[(long)r * Nout + c] = f2b(v);
                }
            }
        }
    }
}

// ================= column mean =================
__global__ __launch_bounds__(256) void col_mean(const float* __restrict__ y,
                                                float* __restrict__ mean_x,
                                                int rows, int cols) {
    int j = blockIdx.x;
    float s = 0.f;
    for (int i = threadIdx.x; i < rows; i += blockDim.x) s += y[(long)i * cols + j];
    __shared__ float red[256];
    red[threadIdx.x] = s;
    __syncthreads();
    for (int o = 128; o > 0; o >>= 1) {
        if (threadIdx.x < o) red[threadIdx.x] += red[threadIdx.x + o];
        __syncthreads();
    }
    if (threadIdx.x == 0) mean_x[j] = red[0] / (float)rows;
}

// ================= reg loss =================
__global__ __launch_bounds__(256) void reg_loss_k(const float* __restrict__ h,
                                                  const float* __restrict__ u_sum,
                                                  const float* __restrict__ mean_x,
                                                  float* __restrict__ acc,
                                                  int rows, int cols, float inv_n3) {
    long total = (long)rows * cols;
    long idx = (long)blockIdx.x * blockDim.x + threadIdx.x;
    long stride = (long)gridDim.x * blockDim.x;
    float s = 0.f;
    for (long t = idx; t < total; t += stride) {
        int i = (int)(t / cols);
        int j = (int)(t - (long)i * cols);
        float mu = u_sum[i] * inv_n3;
        float d = mu * h[t] - mean_x[j];
        s += d * d;
    }
    __shared__ float red[256];
    red[threadIdx.x] = s;
    __syncthreads();
    for (int o = 128; o > 0; o >>= 1) {
        if (threadIdx.x < o) red[threadIdx.x] += red[threadIdx.x + o];
        __syncthreads();
    }
    if (threadIdx.x == 0) atomicAdd(acc, red[0]);
}

__global__ void finalize_k(float* __restrict__ out, const float* __restrict__ acc, float scale) {
    if (threadIdx.x == 0) *out = *acc * scale;
}

extern "C" void kernel_launch(void* const* d_in, const int* in_sizes, int n_in,
                              void* d_out, int out_size, void* d_ws, size_t ws_size,
                              hipStream_t stream) {
    const float* x   = (const float*)d_in[0];
    const float* W1  = (const float*)d_in[1];
    const float* b1  = (const float*)d_in[2];
    const float* W2  = (const float*)d_in[3];
    const float* b2  = (const float*)d_in[4];
    const float* W3  = (const float*)d_in[5];
    const float* b3  = (const float*)d_in[6];
    const float* ew1 = (const float*)d_in[7];
    const float* ew2 = (const float*)d_in[8];
    const float* ew3 = (const float*)d_in[9];
    const float* u_sum = (const float*)d_in[10];
    const int* s1 = (const int*)d_in[11];
    const int* d1 = (const int*)d_in[12];
    const int* s2 = (const int*)d_in[13];
    const int* d2 = (const int*)d_in[14];
    const int* s3 = (const int*)d_in[15];
    const int* d3 = (const int*)d_in[16];

    const int K  = 256;
    const int n0 = in_sizes[0] / K;          // 100000
    const int E1 = in_sizes[7];              // 800000
    const int E2 = in_sizes[8];              // 400000
    const int E3 = in_sizes[9];              // 200000
    const int n2 = in_sizes[10];             // 25000
    const int NC = in_sizes[5] / K;          // 47
    const int n3 = (out_size - 1) / NC;      // 12500
    const int n1 = 50000;                    // fixed by problem

    const int NT = n1 + n2 + n3;
    const int Et = E1 + E2 + E3;
    const int NBKT = (NT + 63) >> 6;         // coarse buckets of 64 dsts
    const int nscan = NBKT * NBLK_S;
    const int nb = (nscan + 1023) / 1024;
    const int chunk = (Et + NBLK_S - 1) / NBLK_S;
    const int Gf2b = 1024;

    // ---- workspace layout ----
    float* ws = (float*)d_ws;
    long o = 0;
    auto take = [&](long words) { float* p = ws + o; o += (words + 3) & ~3L; return p; };
    int*    off  = (int*)take(NT + 1);
    int*    bh   = (int*)take(nscan);
    int*    bhs  = (int*)take(nscan);
    int*    bsum = (int*)take(nb);
    int*    bbase= (int*)take(nb);
    int*    bs_g = (int*)take(Et);
    int2*   bs_sw= (int2*)take(2L * Et);
    int2*   csr  = (int2*)take(2L * Et);
    float*  rw   = take(n1 + n2);
    ushort* Wt1b = (ushort*)take(256 * 256 / 2);
    ushort* Wt2b = (ushort*)take(256 * 256 / 2);
    ushort* Wt3b = (ushort*)take(128 * 256 / 2);
    float*  b3p  = take(128);
    ushort* aggb = (ushort*)take((long)n1 * 256 / 2);
    ushort* xb   = (ushort*)take((long)n0 * 256 / 2);
    float*  h3   = take((long)n2 * NC);
    float*  mean_x = take(64);
    float*  accs   = take(4);

    ushort* y1b = xb;                           // xb dead after gather1
    ushort* y2b = xb + (long)n1 * 256;
    float*  rw1 = rw;
    float*  rw2 = rw + n1;

    float* y3   = (float*)d_out;
    float* loss = y3 + (long)n3 * NC;

    dim3 blk(256);

    // ---- fused prep: f2b | wtrans | bucket hist ----
    prep_k<<<dim3(Gf2b + 256 + NBLK_S), dim3(1024), 0, stream>>>(
        x, xb, (long)n0 * 256 / 8,
        W1, W2, W3, b3, Wt1b, Wt2b, Wt3b, b3p, NC,
        d1, d2, d3, E1, E2, E3, n1, n2, bh, NBKT, chunk, Gf2b);

    // ---- scan bh (bucket-major) ----
    scan1<<<dim3(nb), dim3(1024), 0, stream>>>(bh, bhs, bsum, nscan);
    scan2b<<<dim3(1), dim3(1024), 0, stream>>>(bsum, bbase, nb, &off[NT], accs);
    scan3<<<dim3(256), blk, 0, stream>>>(bhs, bbase, nscan);

    // ---- bucket-sort edges, then in-bucket counting sort -> CSR + off ----
    sortC<<<dim3(NBLK_S), dim3(1024), 0, stream>>>(s1, d1, s2, d2, s3, d3, ew1, ew2, ew3,
                                                   bhs, bs_g, bs_sw, E1, E2, E3, n1, n2, NBKT, chunk);
    sortD<<<dim3(NBKT), blk, 0, stream>>>(bhs, bs_g, bs_sw, off, csr, NBKT, NT, Et);

    // ---- layer 1: agg1 = S1@xb (rw1 = S1 rowsums) ; y1b = relu(agg1@W1 + rw1⊗b1) ----
    gather_b4<<<dim3((n1 + 3) / 4), blk, 0, stream>>>(xb, off, csr, aggb, rw1, n1);
    gemm_mfma<true, false, true, false><<<dim3((n1 + 127) / 128, 2), blk, 0, stream>>>(
        aggb, Wt1b, b1, rw1, y1b, nullptr, n1, 256, K);

    // ---- layer 2 ----
    gather_b4<<<dim3((n2 + 3) / 4), blk, 0, stream>>>(y1b, off + n1, csr, aggb, rw2, n2);
    gemm_mfma<true, false, true, false><<<dim3((n2 + 127) / 128, 2), blk, 0, stream>>>(
        aggb, Wt2b, b2, rw2, y2b, nullptr, n2, 256, K);

    // ---- layer 3 ----
    gemm_mfma<false, true, false, true><<<dim3((n2 + 127) / 128, 1), blk, 0, stream>>>(
        y2b, Wt3b, b3p, nullptr, nullptr, h3, n2, NC, K);
    gather_small<<<dim3((n3 + 3) / 4), blk, 0, stream>>>(h3, off + n1 + n2, csr, y3, n3, NC);

    // ---- reg loss ----
    col_mean<<<dim3(NC), blk, 0, stream>>>(y3, mean_x, n3, NC);
    reg_loss_k<<<dim3(512), blk, 0, stream>>>(h3, u_sum, mean_x, accs, n2, NC, 1.0f / (float)n3);
    finalize_k<<<dim3(1), dim3(1), 0, stream>>>(loss, accs, 1.0f / ((float)n2 * (float)NC));
}

// Round 9
// 292.098 us; speedup vs baseline: 1.0175x; 1.0175x over previous
//
#include <hip/hip_runtime.h>

typedef unsigned int uint;
typedef __attribute__((ext_vector_type(8))) short bf16x8;
typedef __attribute__((ext_vector_type(4))) float f32x4;

__device__ __forceinline__ float b2f(ushort h) { return __uint_as_float(((uint)h) << 16); }
__device__ __forceinline__ ushort f2b(float f) {
    uint u = __float_as_uint(f);
    return (ushort)((u + 0x7fffu + ((u >> 16) & 1u)) >> 16);
}

#define NBLK_S 256   // sort blocks (pass A / pass C)

// ================= fused prep: f2b(x) | wtrans | pass A (LDS bucket hist) =================
__global__ __launch_bounds__(1024) void prep_k(
    const float* __restrict__ x, ushort* __restrict__ xb, long n8,
    const float* __restrict__ W1, const float* __restrict__ W2,
    const float* __restrict__ W3, const float* __restrict__ b3,
    ushort* __restrict__ Wt1, ushort* __restrict__ Wt2,
    ushort* __restrict__ Wt3, float* __restrict__ b3p, int NC,
    const int* __restrict__ d1, const int* __restrict__ d2, const int* __restrict__ d3,
    int E1, int E2, int E3, int n1, int n2,
    int* __restrict__ bh, int NBKT, int chunk, int Gf2b) {
    __shared__ int hist[2048];
    int b = blockIdx.x;
    if (b < Gf2b) {
        long i = (long)b * 1024 + threadIdx.x;
        long st = (long)Gf2b * 1024;
        for (; i < n8; i += st) {
            float4 a = reinterpret_cast<const float4*>(x)[i * 2];
            float4 c = reinterpret_cast<const float4*>(x)[i * 2 + 1];
            ushort4 o0, o1;
            o0.x = f2b(a.x); o0.y = f2b(a.y); o0.z = f2b(a.z); o0.w = f2b(a.w);
            o1.x = f2b(c.x); o1.y = f2b(c.y); o1.z = f2b(c.z); o1.w = f2b(c.w);
            reinterpret_cast<ushort4*>(xb)[i * 2] = o0;
            reinterpret_cast<ushort4*>(xb)[i * 2 + 1] = o1;
        }
        return;
    }
    b -= Gf2b;
    if (b < 256) {
        int k = b;
        int t = threadIdx.x;
        if (t < 256) {
            Wt1[(long)t * 256 + k] = f2b(W1[(long)k * 256 + t]);
        } else if (t < 512) {
            int n = t - 256;
            Wt2[(long)n * 256 + k] = f2b(W2[(long)k * 256 + n]);
        } else if (t < 640) {
            int n = t - 512;
            float v = (n < NC) ? W3[(long)k * NC + n] : 0.f;
            Wt3[(long)n * 256 + k] = f2b(v);
            if (k == 0) b3p[n] = (n < NC) ? b3[n] : 0.f;
        }
        return;
    }
    b -= 256;
    const int Et = E1 + E2 + E3;
    const int c0 = b * chunk;
    const int c1 = (c0 + chunk < Et) ? c0 + chunk : Et;
    for (int i = threadIdx.x; i < NBKT; i += 1024) hist[i] = 0;
    __syncthreads();
    for (int i = c0 + (int)threadIdx.x; i < c1; i += 1024) {
        int g;
        if (i < E1) g = d1[i];
        else if (i < E1 + E2) g = n1 + d2[i - E1];
        else g = n1 + n2 + d3[i - E1 - E2];
        atomicAdd(&hist[g >> 6], 1);
    }
    __syncthreads();
    for (int k = threadIdx.x; k < NBKT; k += 1024) bh[k * NBLK_S + b] = hist[k];
}

// ---- scan phase 1 ----
__global__ __launch_bounds__(1024) void scan1(const int* __restrict__ cnt, int* __restrict__ off,
                                              int* __restrict__ bsum, int n) {
    __shared__ int wsum[16];
    const int lane = threadIdx.x & 63;
    const int wid = threadIdx.x >> 6;
    int i = blockIdx.x * 1024 + threadIdx.x;
    int v = (i < n) ? cnt[i] : 0;
    int s = v;
    #pragma unroll
    for (int o = 1; o < 64; o <<= 1) {
        int t = __shfl_up(s, o, 64);
        if (lane >= o) s += t;
    }
    if (lane == 63) wsum[wid] = s;
    __syncthreads();
    if (wid == 0 && lane < 16) {
        int t = wsum[lane];
        #pragma unroll
        for (int o = 1; o < 16; o <<= 1) {
            int u = __shfl_up(t, o, 64);
            if (lane >= o) t += u;
        }
        wsum[lane] = t;
    }
    __syncthreads();
    int woff = (wid > 0) ? wsum[wid - 1] : 0;
    if (i < n) off[i] = woff + s - v;
    if (threadIdx.x == 0) bsum[blockIdx.x] = wsum[15];
}

// ---- scan phase 2: scans block sums into bbase; off[NT] = grand total; acc = 0 ----
__global__ __launch_bounds__(1024) void scan2b(const int* __restrict__ bsum, int* __restrict__ bbase,
                                               int n, int* __restrict__ offNT, float* __restrict__ acc) {
    __shared__ int wsum[16];
    int tid = threadIdx.x;
    int lane = tid & 63;
    int wid = tid >> 6;
    int v = (tid < n) ? bsum[tid] : 0;
    int s = v;
    #pragma unroll
    for (int o = 1; o < 64; o <<= 1) {
        int t = __shfl_up(s, o, 64);
        if (lane >= o) s += t;
    }
    if (lane == 63) wsum[wid] = s;
    __syncthreads();
    if (wid == 0 && lane < 16) {
        int t = wsum[lane];
        #pragma unroll
        for (int o = 1; o < 16; o <<= 1) {
            int u = __shfl_up(t, o, 64);
            if (lane >= o) t += u;
        }
        wsum[lane] = t;
    }
    __syncthreads();
    int base = (wid > 0) ? wsum[wid - 1] : 0;
    int excl = base + s - v;
    if (tid < n) bbase[tid] = excl;
    if (tid == n - 1) *offNT = excl + v;
    if (tid == 0) *acc = 0.f;
}

// ================= pass C: place edges bucket-sorted (adds bbase inline) =================
__global__ __launch_bounds__(1024) void sortC(
    const int* __restrict__ s1, const int* __restrict__ d1,
    const int* __restrict__ s2, const int* __restrict__ d2,
    const int* __restrict__ s3, const int* __restrict__ d3,
    const float* __restrict__ w1, const float* __restrict__ w2, const float* __restrict__ w3,
    const int* __restrict__ bhs, const int* __restrict__ bbase,
    int* __restrict__ bs_g, int2* __restrict__ bs_sw,
    int E1, int E2, int E3, int n1, int n2, int NBKT, int chunk) {
    __shared__ int cur[2048];
    const int b = blockIdx.x;
    const int Et = E1 + E2 + E3;
    const int c0 = b * chunk;
    const int c1 = (c0 + chunk < Et) ? c0 + chunk : Et;
    for (int k = threadIdx.x; k < NBKT; k += 1024) {
        int idx = k * NBLK_S + b;
        cur[k] = bhs[idx] + bbase[idx >> 10];
    }
    __syncthreads();
    for (int i = c0 + (int)threadIdx.x; i < c1; i += 1024) {
        int g, s, w;
        if (i < E1) { g = d1[i]; s = s1[i]; w = __float_as_int(w1[i]); }
        else if (i < E1 + E2) { int j = i - E1; g = n1 + d2[j]; s = s2[j]; w = __float_as_int(w2[j]); }
        else { int j = i - E1 - E2; g = n1 + n2 + d3[j]; s = s3[j]; w = __float_as_int(w3[j]); }
        int p = atomicAdd(&cur[g >> 6], 1);
        bs_g[p] = g;
        bs_sw[p] = make_int2(s, w);
    }
}

// ================= pass D: in-bucket counting sort -> final CSR + off (adds bbase inline) =================
__global__ __launch_bounds__(256) void sortD(const int* __restrict__ bhs, const int* __restrict__ bbase,
                                             const int* __restrict__ bs_g,
                                             const int2* __restrict__ bs_sw,
                                             int* __restrict__ off, int2* __restrict__ csr,
                                             int NBKT, int NT, int Et) {
    __shared__ int hist[64];
    __shared__ int cur[64];
    const int b = blockIdx.x;
    const int g0 = b << 6;
    int i0 = b * NBLK_S;
    const int B0 = bhs[i0] + bbase[i0 >> 10];
    int i1 = (b + 1) * NBLK_S;
    const int B1 = (b == NBKT - 1) ? Et : bhs[i1] + bbase[i1 >> 10];
    const int tid = threadIdx.x;
    if (tid < 64) hist[tid] = 0;
    __syncthreads();
    for (int p = B0 + tid; p < B1; p += 256) atomicAdd(&hist[bs_g[p] - g0], 1);
    __syncthreads();
    if (tid < 64) {
        int v = hist[tid];
        int s = v;
        #pragma unroll
        for (int o = 1; o < 64; o <<= 1) {
            int t = __shfl_up(s, o, 64);
            if (tid >= o) s += t;
        }
        int excl = B0 + s - v;
        cur[tid] = excl;
        int g = g0 + tid;
        if (g < NT) off[g] = excl;
    }
    __syncthreads();
    for (int p = B0 + tid; p < B1; p += 256) {
        int r = bs_g[p] - g0;
        int q = atomicAdd(&cur[r], 1);
        csr[q] = bs_sw[p];
    }
}

// ================= gather, bf16, F == 256: scalar edges + half-wave pairing + ILP-16 =================
__global__ __launch_bounds__(256) void gather_b4(const ushort* __restrict__ hb,
                                                 const int* __restrict__ off,
                                                 const int2* __restrict__ csr,
                                                 ushort* __restrict__ out,
                                                 float* __restrict__ rw, int n_dst) {
    const int d = __builtin_amdgcn_readfirstlane(blockIdx.x * 4 + (threadIdx.x >> 6));
    if (d >= n_dst) return;
    const int lane = threadIdx.x & 63;
    const int half = lane >> 5;
    const int fl = lane & 31;
    const int i0 = off[d], i1 = off[d + 1];
    float acc[8] = {0.f, 0.f, 0.f, 0.f, 0.f, 0.f, 0.f, 0.f};
    float sw = 0.f;
    const ushort* hrow = hb + fl * 8;

#define FMA8(v_, w_)                                                          \
    {                                                                         \
        uint u_;                                                              \
        u_ = (uint)(v_).x;                                                    \
        acc[0] += (w_) * __uint_as_float(u_ << 16);                           \
        acc[1] += (w_) * __uint_as_float(u_ & 0xffff0000u);                   \
        u_ = (uint)(v_).y;                                                    \
        acc[2] += (w_) * __uint_as_float(u_ << 16);                           \
        acc[3] += (w_) * __uint_as_float(u_ & 0xffff0000u);                   \
        u_ = (uint)(v_).z;                                                    \
        acc[4] += (w_) * __uint_as_float(u_ << 16);                           \
        acc[5] += (w_) * __uint_as_float(u_ & 0xffff0000u);                   \
        u_ = (uint)(v_).w;                                                    \
        acc[6] += (w_) * __uint_as_float(u_ << 16);                           \
        acc[7] += (w_) * __uint_as_float(u_ & 0xffff0000u);                   \
    }

    int i = i0;
    // ---- fat tier: 16 edges = 8 pairs, 8 row-loads in flight ----
    for (; i + 16 <= i1; i += 16) {
        int2 e[16];
        #pragma unroll
        for (int u = 0; u < 16; ++u) e[u] = csr[i + u];      // scalar loads
        int4 v[8]; float wv[8];
        #pragma unroll
        for (int p = 0; p < 8; ++p) {
            float w0 = __int_as_float(e[2 * p].y);
            float w1 = __int_as_float(e[2 * p + 1].y);
            int row = half ? e[2 * p + 1].x : e[2 * p].x;
            wv[p] = half ? w1 : w0;
            v[p] = *reinterpret_cast<const int4*>(&hrow[(long)row * 256]);
            sw += w0 + w1;
        }
        #pragma unroll
        for (int p = 0; p < 8; ++p) FMA8(v[p], wv[p]);
    }
    // ---- 4-pair tier (8 edges) ----
    for (; i + 8 <= i1; i += 8) {
        int2 e[8];
        #pragma unroll
        for (int u = 0; u < 8; ++u) e[u] = csr[i + u];
        int4 v[4]; float wv[4];
        #pragma unroll
        for (int p = 0; p < 4; ++p) {
            float w0 = __int_as_float(e[2 * p].y);
            float w1 = __int_as_float(e[2 * p + 1].y);
            int row = half ? e[2 * p + 1].x : e[2 * p].x;
            wv[p] = half ? w1 : w0;
            v[p] = *reinterpret_cast<const int4*>(&hrow[(long)row * 256]);
            sw += w0 + w1;
        }
        #pragma unroll
        for (int p = 0; p < 4; ++p) FMA8(v[p], wv[p]);
    }
    // ---- pair tier ----
    for (; i + 2 <= i1; i += 2) {
        int2 e0 = csr[i], e1 = csr[i + 1];
        float w0 = __int_as_float(e0.y), w1 = __int_as_float(e1.y);
        int row = half ? e1.x : e0.x;
        float w_ = half ? w1 : w0;
        int4 v = *reinterpret_cast<const int4*>(&hrow[(long)row * 256]);
        FMA8(v, w_);
        sw += w0 + w1;
    }
    // ---- odd tail ----
    if (i < i1) {
        int2 e0 = csr[i];
        float w0 = __int_as_float(e0.y);
        float w_ = half ? 0.f : w0;
        int4 v = *reinterpret_cast<const int4*>(&hrow[(long)e0.x * 256]);
        FMA8(v, w_);
        sw += w0;
    }
#undef FMA8

    #pragma unroll
    for (int k = 0; k < 8; ++k) acc[k] += __shfl_xor(acc[k], 32, 64);
    if (lane == 0) rw[d] = sw;
    if (half == 0) {
        int4 o;
        o.x = (int)((uint)f2b(acc[0]) | ((uint)f2b(acc[1]) << 16));
        o.y = (int)((uint)f2b(acc[2]) | ((uint)f2b(acc[3]) << 16));
        o.z = (int)((uint)f2b(acc[4]) | ((uint)f2b(acc[5]) << 16));
        o.w = (int)((uint)f2b(acc[6]) | ((uint)f2b(acc[7]) << 16));
        *reinterpret_cast<int4*>(&out[(long)d * 256 + fl * 8]) = o;
    }
}

// ================= gather, small F (<=64), f32: scalar edge loads, ILP 8 =================
__global__ __launch_bounds__(256) void gather_small(const float* __restrict__ h,
                                                    const int* __restrict__ off,
                                                    const int2* __restrict__ csr,
                                                    float* __restrict__ y, int n_dst, int F) {
    const int d = __builtin_amdgcn_readfirstlane(blockIdx.x * 4 + (threadIdx.x >> 6));
    if (d >= n_dst) return;
    const int lane = threadIdx.x & 63;
    const int i0 = off[d], i1 = off[d + 1];
    const bool act = lane < F;
    float acc = 0.f;
    int i = i0;
    for (; i + 8 <= i1; i += 8) {
        int2 e[8];
        #pragma unroll
        for (int u = 0; u < 8; ++u) e[u] = csr[i + u];
        float v[8];
        #pragma unroll
        for (int u = 0; u < 8; ++u) v[u] = act ? h[(long)e[u].x * F + lane] : 0.f;
        #pragma unroll
        for (int u = 0; u < 8; ++u) acc += __int_as_float(e[u].y) * v[u];
    }
    for (; i < i1; ++i) {
        int2 e = csr[i];
        if (act) acc += __int_as_float(e.y) * h[(long)e.x * F + lane];
    }
    if (act) y[(long)d * F + lane] = acc;
}

// ================= bf16 MFMA GEMM: C = act(A @ Bt^T + rowsc⊗bias) =================
template <bool RELU, bool OUTF32, bool ROWSC, bool GUARDN>
__global__ __launch_bounds__(256) void gemm_mfma(const ushort* __restrict__ A,
                                                 const ushort* __restrict__ Bt,
                                                 const float* __restrict__ bias,
                                                 const float* __restrict__ rowsc,
                                                 ushort* __restrict__ Cb,
                                                 float* __restrict__ Cf,
                                                 int M, int Nout, int K) {
    __shared__ ushort As[4096];
    __shared__ ushort Bs[4096];
    const int tid = threadIdx.x;
    const int w = tid >> 6;
    const int lane = tid & 63;
    const int l15 = lane & 15;
    const int l4 = lane >> 4;
    const int bm = blockIdx.x * 128;
    const int bn = blockIdx.y * 128;
    const int wm = w >> 1, wn = w & 1;

    int ra0 = bm + w * 16 + l15;       if (ra0 >= M) ra0 = M - 1;
    int ra1 = bm + (w + 4) * 16 + l15; if (ra1 >= M) ra1 = M - 1;
    const ushort* pa0 = A + (long)ra0 * K + l4 * 8;
    const ushort* pa1 = A + (long)ra1 * K + l4 * 8;
    const ushort* pb0 = Bt + (long)(bn + w * 16 + l15) * K + l4 * 8;
    const ushort* pb1 = Bt + (long)(bn + (w + 4) * 16 + l15) * K + l4 * 8;

    f32x4 acc[4][4];
    f32x4 zz = {0.f, 0.f, 0.f, 0.f};
    #pragma unroll
    for (int m = 0; m < 4; ++m)
        #pragma unroll
        for (int n = 0; n < 4; ++n) acc[m][n] = zz;

    for (int k0 = 0; k0 < K; k0 += 32) {
        __builtin_amdgcn_global_load_lds((const __attribute__((address_space(1))) void*)pa0,
                                         (__attribute__((address_space(3))) void*)&As[w * 512], 16, 0, 0);
        __builtin_amdgcn_global_load_lds((const __attribute__((address_space(1))) void*)pa1,
                                         (__attribute__((address_space(3))) void*)&As[(w + 4) * 512], 16, 0, 0);
        __builtin_amdgcn_global_load_lds((const __attribute__((address_space(1))) void*)pb0,
                                         (__attribute__((address_space(3))) void*)&Bs[w * 512], 16, 0, 0);
        __builtin_amdgcn_global_load_lds((const __attribute__((address_space(1))) void*)pb1,
                                         (__attribute__((address_space(3))) void*)&Bs[(w + 4) * 512], 16, 0, 0);
        pa0 += 32; pa1 += 32; pb0 += 32; pb1 += 32;
        __syncthreads();
        bf16x8 af[4], bfr[4];
        #pragma unroll
        for (int m = 0; m < 4; ++m)
            af[m] = *reinterpret_cast<const bf16x8*>(&As[(wm * 4 + m) * 512 + lane * 8]);
        #pragma unroll
        for (int n = 0; n < 4; ++n)
            bfr[n] = *reinterpret_cast<const bf16x8*>(&Bs[(wn * 4 + n) * 512 + lane * 8]);
        #pragma unroll
        for (int m = 0; m < 4; ++m)
            #pragma unroll
            for (int n = 0; n < 4; ++n)
                acc[m][n] = __builtin_amdgcn_mfma_f32_16x16x32_bf16(af[m], bfr[n], acc[m][n], 0, 0, 0);
        __syncthreads();
    }

    const int rbase = bm + wm * 64;
    const int cbase = bn + wn * 64;
    #pragma unroll
    for (int m = 0; m < 4; ++m) {
        #pragma unroll
        for (int q = 0; q < 4; ++q) {
            int r = rbase + m * 16 + l4 * 4 + q;
            if (r >= M) continue;
            float rs = ROWSC ? rowsc[r] : 1.f;
            #pragma unroll
            for (int n = 0; n < 4; ++n) {
                int c = cbase + n * 16 + l15;
                float v = acc[m][n][q] + rs * bias[c];
                if (RELU) v = fmaxf(v, 0.f);
                if (!GUARDN || c < Nout) {
                    if (OUTF32) Cf[(long)r * Nout + c] = v;
                    else Cb[(long)r * Nout + c] = f2b(v);
                }
            }
        }
    }
}

// ================= column mean =================
__global__ __launch_bounds__(256) void col_mean(const float* __restrict__ y,
                                                float* __restrict__ mean_x,
                                                int rows, int cols) {
    int j = blockIdx.x;
    float s = 0.f;
    for (int i = threadIdx.x; i < rows; i += blockDim.x) s += y[(long)i * cols + j];
    __shared__ float red[256];
    red[threadIdx.x] = s;
    __syncthreads();
    for (int o = 128; o > 0; o >>= 1) {
        if (threadIdx.x < o) red[threadIdx.x] += red[threadIdx.x + o];
        __syncthreads();
    }
    if (threadIdx.x == 0) mean_x[j] = red[0] / (float)rows;
}

// ================= reg loss =================
__global__ __launch_bounds__(256) void reg_loss_k(const float* __restrict__ h,
                                                  const float* __restrict__ u_sum,
                                                  const float* __restrict__ mean_x,
                                                  float* __restrict__ acc,
                                                  int rows, int cols, float inv_n3) {
    long total = (long)rows * cols;
    long idx = (long)blockIdx.x * blockDim.x + threadIdx.x;
    long stride = (long)gridDim.x * blockDim.x;
    float s = 0.f;
    for (long t = idx; t < total; t += stride) {
        int i = (int)(t / cols);
        int j = (int)(t - (long)i * cols);
        float mu = u_sum[i] * inv_n3;
        float d = mu * h[t] - mean_x[j];
        s += d * d;
    }
    __shared__ float red[256];
    red[threadIdx.x] = s;
    __syncthreads();
    for (int o = 128; o > 0; o >>= 1) {
        if (threadIdx.x < o) red[threadIdx.x] += red[threadIdx.x + o];
        __syncthreads();
    }
    if (threadIdx.x == 0) atomicAdd(acc, red[0]);
}

__global__ void finalize_k(float* __restrict__ out, const float* __restrict__ acc, float scale) {
    if (threadIdx.x == 0) *out = *acc * scale;
}

extern "C" void kernel_launch(void* const* d_in, const int* in_sizes, int n_in,
                              void* d_out, int out_size, void* d_ws, size_t ws_size,
                              hipStream_t stream) {
    const float* x   = (const float*)d_in[0];
    const float* W1  = (const float*)d_in[1];
    const float* b1  = (const float*)d_in[2];
    const float* W2  = (const float*)d_in[3];
    const float* b2  = (const float*)d_in[4];
    const float* W3  = (const float*)d_in[5];
    const float* b3  = (const float*)d_in[6];
    const float* ew1 = (const float*)d_in[7];
    const float* ew2 = (const float*)d_in[8];
    const float* ew3 = (const float*)d_in[9];
    const float* u_sum = (const float*)d_in[10];
    const int* s1 = (const int*)d_in[11];
    const int* d1 = (const int*)d_in[12];
    const int* s2 = (const int*)d_in[13];
    const int* d2 = (const int*)d_in[14];
    const int* s3 = (const int*)d_in[15];
    const int* d3 = (const int*)d_in[16];

    const int K  = 256;
    const int n0 = in_sizes[0] / K;          // 100000
    const int E1 = in_sizes[7];              // 800000
    const int E2 = in_sizes[8];              // 400000
    const int E3 = in_sizes[9];              // 200000
    const int n2 = in_sizes[10];             // 25000
    const int NC = in_sizes[5] / K;          // 47
    const int n3 = (out_size - 1) / NC;      // 12500
    const int n1 = 50000;                    // fixed by problem

    const int NT = n1 + n2 + n3;
    const int Et = E1 + E2 + E3;
    const int NBKT = (NT + 63) >> 6;         // coarse buckets of 64 dsts
    const int nscan = NBKT * NBLK_S;
    const int nb = (nscan + 1023) / 1024;
    const int chunk = (Et + NBLK_S - 1) / NBLK_S;
    const int Gf2b = 1024;

    // ---- workspace layout ----
    float* ws = (float*)d_ws;
    long o = 0;
    auto take = [&](long words) { float* p = ws + o; o += (words + 3) & ~3L; return p; };
    int*    off  = (int*)take(NT + 1);
    int*    bh   = (int*)take(nscan);
    int*    bhs  = (int*)take(nscan);
    int*    bsum = (int*)take(nb);
    int*    bbase= (int*)take(nb);
    int*    bs_g = (int*)take(Et);
    int2*   bs_sw= (int2*)take(2L * Et);
    int2*   csr  = (int2*)take(2L * Et);
    float*  rw   = take(n1 + n2);
    ushort* Wt1b = (ushort*)take(256 * 256 / 2);
    ushort* Wt2b = (ushort*)take(256 * 256 / 2);
    ushort* Wt3b = (ushort*)take(128 * 256 / 2);
    float*  b3p  = take(128);
    ushort* aggb = (ushort*)take((long)n1 * 256 / 2);
    ushort* xb   = (ushort*)take((long)n0 * 256 / 2);
    float*  h3   = take((long)n2 * NC);
    float*  mean_x = take(64);
    float*  accs   = take(4);

    ushort* y1b = xb;                           // xb dead after gather1
    ushort* y2b = xb + (long)n1 * 256;
    float*  rw1 = rw;
    float*  rw2 = rw + n1;

    float* y3   = (float*)d_out;
    float* loss = y3 + (long)n3 * NC;

    dim3 blk(256);

    // ---- fused prep: f2b | wtrans | bucket hist ----
    prep_k<<<dim3(Gf2b + 256 + NBLK_S), dim3(1024), 0, stream>>>(
        x, xb, (long)n0 * 256 / 8,
        W1, W2, W3, b3, Wt1b, Wt2b, Wt3b, b3p, NC,
        d1, d2, d3, E1, E2, E3, n1, n2, bh, NBKT, chunk, Gf2b);

    // ---- scan bh (bucket-major); bbase folded into sortC/sortD ----
    scan1<<<dim3(nb), dim3(1024), 0, stream>>>(bh, bhs, bsum, nscan);
    scan2b<<<dim3(1), dim3(1024), 0, stream>>>(bsum, bbase, nb, &off[NT], accs);

    // ---- bucket-sort edges, then in-bucket counting sort -> CSR + off ----
    sortC<<<dim3(NBLK_S), dim3(1024), 0, stream>>>(s1, d1, s2, d2, s3, d3, ew1, ew2, ew3,
                                                   bhs, bbase, bs_g, bs_sw, E1, E2, E3, n1, n2, NBKT, chunk);
    sortD<<<dim3(NBKT), blk, 0, stream>>>(bhs, bbase, bs_g, bs_sw, off, csr, NBKT, NT, Et);

    // ---- layer 1: agg1 = S1@xb (rw1 = S1 rowsums) ; y1b = relu(agg1@W1 + rw1⊗b1) ----
    gather_b4<<<dim3((n1 + 3) / 4), blk, 0, stream>>>(xb, off, csr, aggb, rw1, n1);
    gemm_mfma<true, false, true, false><<<dim3((n1 + 127) / 128, 2), blk, 0, stream>>>(
        aggb, Wt1b, b1, rw1, y1b, nullptr, n1, 256, K);

    // ---- layer 2 ----
    gather_b4<<<dim3((n2 + 3) / 4), blk, 0, stream>>>(y1b, off + n1, csr, aggb, rw2, n2);
    gemm_mfma<true, false, true, false><<<dim3((n2 + 127) / 128, 2), blk, 0, stream>>>(
        aggb, Wt2b, b2, rw2, y2b, nullptr, n2, 256, K);

    // ---- layer 3 ----
    gemm_mfma<false, true, false, true><<<dim3((n2 + 127) / 128, 1), blk, 0, stream>>>(
        y2b, Wt3b, b3p, nullptr, nullptr, h3, n2, NC, K);
    gather_small<<<dim3((n3 + 3) / 4), blk, 0, stream>>>(h3, off + n1 + n2, csr, y3, n3, NC);

    // ---- reg loss ----
    col_mean<<<dim3(NC), blk, 0, stream>>>(y3, mean_x, n3, NC);
    reg_loss_k<<<dim3(512), blk, 0, stream>>>(h3, u_sum, mean_x, accs, n2, NC, 1.0f / (float)n3);
    finalize_k<<<dim3(1), dim3(1), 0, stream>>>(loss, accs, 1.0f / ((float)n2 * (float)NC));
}